// Round 4
// baseline (518.484 us; speedup 1.0000x reference)
//
#include <hip/hip_runtime.h>
#include <stdint.h>

#define NND 200000   // N nodes; D_IN = D_OUT = 256, B = 256

typedef unsigned short u16;
typedef __attribute__((ext_vector_type(4))) float f4;
typedef __attribute__((ext_vector_type(4))) int   i4;
typedef __attribute__((ext_vector_type(2))) unsigned int u2;
typedef __attribute__((ext_vector_type(8))) short s8;   // 8 bf16 - MFMA A/B frag
typedef __attribute__((ext_vector_type(4))) float acc4; // MFMA C/D frag

__device__ __forceinline__ short f2bf(float f) {
    union { float f; uint32_t u; } v; v.f = f;
    uint32_t r = v.u + 0x7FFFu + ((v.u >> 16) & 1u);   // RNE
    return (short)(r >> 16);
}
__device__ __forceinline__ uint32_t pack2bf(float a, float b) {
    uint32_t ua = __float_as_uint(a), ub = __float_as_uint(b);
    ua = ua + 0x7FFFu + ((ua >> 16) & 1u);
    ub = ub + 0x7FFFu + ((ub >> 16) & 1u);
    return (ua >> 16) | (ub & 0xFFFF0000u);
}
__device__ __forceinline__ void gld16(const void* g, void* l) {
    __builtin_amdgcn_global_load_lds(
        (const __attribute__((address_space(1))) void*)g,
        (__attribute__((address_space(3))) void*)l, 16, 0, 0);
}

// ---------------- prep: W fp32 -> bf16 ----------------
__global__ __launch_bounds__(256) void k_prep(const float* __restrict__ Wt,
                                              const float* __restrict__ Wg,
                                              u16* __restrict__ wtb,
                                              u16* __restrict__ wgb) {
    int i = blockIdx.x * 256 + threadIdx.x;   // 256 blocks -> 65536 exactly
    wtb[i] = (u16)f2bf(Wt[i]);
    wgb[i] = (u16)f2bf(Wg[i]);
}

// ---------------- pass 1: h_t[d][n] = (nodes@Wt.T+bt)*sigmoid(nodes@Wg.T+bg) ----------------
// 256 threads = 4 waves. Block: 64 nodes x 256 d x both matrices.
// Wave w: 64 d (w*64..), all 64 n, T and G. acc = 128 VGPR/lane.
// LDS 74752 -> 2 blocks/CU; launch_bounds(256,2) -> VGPR cap 256.
__global__ __launch_bounds__(256, 2) void k_h(const float* __restrict__ nodes,
                                              const u16* __restrict__ wtb,
                                              const u16* __restrict__ wgb,
                                              const float* __restrict__ btp,
                                              const float* __restrict__ bgp,
                                              u16* __restrict__ h_t) {
    __shared__ __align__(16) char smem[74752];
    u16* Abf = (u16*)smem;               // 64 rows x 144 B (64 bf16 + pad), bank-rotating
    char* Ws = smem + 9216;              // 2 x [256 d x 128 B] bf16, xor-swizzled (gld16 dest)
    u16* Hs  = (u16*)smem;               // epilogue: 256 d x 144 B

    const int tid  = threadIdx.x;
    const int lane = tid & 63, wave = tid >> 6;
    const int quad = lane >> 4, l16 = lane & 15;
    const int n0 = blockIdx.x * 64;

    acc4 at_[4][4], ag_[4][4];
#pragma unroll
    for (int rt = 0; rt < 4; ++rt)
#pragma unroll
        for (int dt = 0; dt < 4; ++dt) { at_[rt][dt] = (acc4)0.0f; ag_[rt][dt] = (acc4)0.0f; }

    for (int kt = 0; kt < 4; ++kt) {
        const int k0 = kt * 64;
        // A prefetch to regs: 4 f4/thread, wave covers 4 full rows per i (coalesced 1KB)
        f4 av[4];
#pragma unroll
        for (int i = 0; i < 4; ++i) {
            int g = i * 256 + tid;
            int row = g >> 4, col = g & 15;   // col = f4 index within 64k
            av[i] = *(const f4*)(nodes + (size_t)(n0 + row) * 256 + k0 + col * 4);
        }
        if (kt) __syncthreads();   // protect LDS from previous round's readers
        // W stage: 2 x 256x64 bf16 via gld16 (L2-hot), 16 gld16/thread
#pragma unroll
        for (int i = 0; i < 8; ++i) {
            int g = i * 256 + tid;
            int dr = g >> 3, c = g & 7;
            size_t off = (size_t)dr * 256 + k0 + ((c ^ (dr & 7)) << 3);
            gld16(wtb + off, Ws + g * 16);
            gld16(wgb + off, Ws + 32768 + g * 16);
        }
        // A convert once -> bf16 LDS (b64 writes, 144-B row stride keeps b128 reads aligned)
#pragma unroll
        for (int i = 0; i < 4; ++i) {
            int g = i * 256 + tid;
            int row = g >> 4, col = g & 15;
            u2 p; p.x = pack2bf(av[i].x, av[i].y); p.y = pack2bf(av[i].z, av[i].w);
            *(u2*)((char*)Abf + row * 144 + (((col >> 1) ^ (row & 7)) << 4) + (col & 1) * 8) = p;
        }
        __syncthreads();
        // MFMA: K=64 in two ks halves; wave owns 64 d, both matrices
#pragma unroll
        for (int ks = 0; ks < 2; ++ks) {
            const int q = (ks << 2) | quad;
            s8 af[4];
#pragma unroll
            for (int rt = 0; rt < 4; ++rt)
                af[rt] = *(const s8*)((char*)Abf + (rt * 16 + l16) * 144 + ((q ^ (l16 & 7)) << 4));
#pragma unroll
            for (int dt = 0; dt < 4; ++dt) {
                int dl = wave * 64 + dt * 16 + l16;
                int sl = (q ^ (dl & 7)) << 4;
                s8 bT = *(const s8*)(Ws + dl * 128 + sl);
                s8 bG = *(const s8*)(Ws + 32768 + dl * 128 + sl);
#pragma unroll
                for (int rt = 0; rt < 4; ++rt) {
                    at_[rt][dt] = __builtin_amdgcn_mfma_f32_16x16x32_bf16(af[rt], bT, at_[rt][dt], 0, 0, 0);
                    ag_[rt][dt] = __builtin_amdgcn_mfma_f32_16x16x32_bf16(af[rt], bG, ag_[rt][dt], 0, 0, 0);
                }
            }
        }
    }
    __syncthreads();   // all waves done reading Ws/Abf before Hs overwrite

    // epilogue: h = (data+bt)*sigmoid(gate+bg) -> bf16 -> LDS transpose
#pragma unroll
    for (int dt = 0; dt < 4; ++dt) {
        int dl = wave * 64 + dt * 16 + l16;
        float btv = btp[dl], bgv = bgp[dl];
#pragma unroll
        for (int rt = 0; rt < 4; ++rt) {
            float h0 = (at_[rt][dt][0] + btv) / (1.0f + __expf(-(ag_[rt][dt][0] + bgv)));
            float h1 = (at_[rt][dt][1] + btv) / (1.0f + __expf(-(ag_[rt][dt][1] + bgv)));
            float h2 = (at_[rt][dt][2] + btv) / (1.0f + __expf(-(ag_[rt][dt][2] + bgv)));
            float h3 = (at_[rt][dt][3] + btv) / (1.0f + __expf(-(ag_[rt][dt][3] + bgv)));
            u2 p; p.x = pack2bf(h0, h1); p.y = pack2bf(h2, h3);
            *(u2*)((char*)Hs + dl * 144 + (rt * 16 + quad * 4) * 2) = p;
        }
    }
    __syncthreads();
    // coalesced store h_t[d][n0..n0+64)
#pragma unroll
    for (int i = 0; i < 8; ++i) {
        int g = i * 256 + tid;
        int d = g >> 3, c = g & 7;
        f4 v = *(const f4*)((char*)Hs + d * 144 + c * 16);
        *(f4*)(h_t + (size_t)d * NND + n0 + c * 8) = v;
    }
}

// ---------------- pass 2: res = mask @ h_t^T, split-K ----------------
// 256 threads = 4 waves. Block: 64 b x 256 d; wave = 64b x 64d. acc 64 VGPR.
// LDS 41984 -> 3 blocks/CU. grid (4, 157): 628 blocks, 20 rounds x 64 n (last split 5).
__global__ __launch_bounds__(256, 3) void k_res(const int* __restrict__ masks,
                                                const u16* __restrict__ h_t,
                                                float* __restrict__ outp) {
    __shared__ __align__(16) char smem[41984];
    u16* Ms = (u16*)smem;             // 64 b x 144 B bf16 (reg-written, bank-rotating)
    char* Hsc = smem + 9216;          // 256 d x 128 B bf16, xor-swizzled (gld16 dest)

    const int tid  = threadIdx.x;
    const int lane = tid & 63, wave = tid >> 6;
    const int quad = lane >> 4, l16 = lane & 15;
    const int b0 = blockIdx.x * 64;
    const int t0 = blockIdx.y * 20;
    const int R = min(20, 3125 - t0);

    acc4 acc[4][4];
#pragma unroll
    for (int rt = 0; rt < 4; ++rt)
#pragma unroll
        for (int dt = 0; dt < 4; ++dt) acc[rt][dt] = (acc4)0.0f;

    // mask granule mapping: g = i*256+tid -> row g>>4 (64 b), seg g&15 (16 i4 per row)
    i4 mp[4];
    {
        const int nb0 = t0 * 64;
#pragma unroll
        for (int i = 0; i < 4; ++i) {
            int g = i * 256 + tid;
            int row = g >> 4, seg = g & 15;
            mp[i] = *(const i4*)(masks + (size_t)(b0 + row) * NND + nb0 + seg * 4);
        }
    }

    for (int it = 0; it < R; ++it) {
        const int nb = (t0 + it) * 64;
        // H: 256x64 bf16 via gld16 (L3-hot), 8/thread
#pragma unroll
        for (int i = 0; i < 8; ++i) {
            int g = i * 256 + tid;
            int dr = g >> 3, c = g & 7;
            gld16(h_t + (size_t)dr * NND + nb + ((c ^ (dr & 7)) << 3), Hsc + g * 16);
        }
        // convert prefetched mask regs -> bf16 LDS (b64 writes, 144-B stride)
#pragma unroll
        for (int i = 0; i < 4; ++i) {
            int g = i * 256 + tid;
            int row = g >> 4, seg = g & 15;
            u2 w;
            w.x = (((uint32_t)(-mp[i].x)) & 0x3F80u) | ((((uint32_t)(-mp[i].y)) & 0x3F80u) << 16);
            w.y = (((uint32_t)(-mp[i].z)) & 0x3F80u) | ((((uint32_t)(-mp[i].w)) & 0x3F80u) << 16);
            *(u2*)((char*)Ms + row * 144 + (((seg >> 1) ^ (row & 7)) << 4) + (seg & 1) * 8) = w;
        }
        __syncthreads();
        // prefetch next round's masks NOW -> HBM latency hidden under MFMA
        if (it + 1 < R) {
            const int nn = nb + 64;
#pragma unroll
            for (int i = 0; i < 4; ++i) {
                int g = i * 256 + tid;
                int row = g >> 4, seg = g & 15;
                mp[i] = *(const i4*)(masks + (size_t)(b0 + row) * NND + nn + seg * 4);
            }
        }
#pragma unroll
        for (int ks = 0; ks < 2; ++ks) {
            const int q = (ks << 2) | quad;
            s8 af[4];
#pragma unroll
            for (int rt = 0; rt < 4; ++rt)
                af[rt] = *(const s8*)((char*)Ms + (rt * 16 + l16) * 144 + ((q ^ (l16 & 7)) << 4));
#pragma unroll
            for (int dt = 0; dt < 4; ++dt) {
                int dl = wave * 64 + dt * 16 + l16;
                s8 bf_ = *(const s8*)(Hsc + dl * 128 + ((q ^ (dl & 7)) << 4));
#pragma unroll
                for (int rt = 0; rt < 4; ++rt)
                    acc[rt][dt] = __builtin_amdgcn_mfma_f32_16x16x32_bf16(af[rt], bf_, acc[rt][dt], 0, 0, 0);
            }
        }
        __syncthreads();
    }
#pragma unroll
    for (int rt = 0; rt < 4; ++rt)
#pragma unroll
        for (int dt = 0; dt < 4; ++dt) {
            int b = b0 + rt * 16 + quad * 4;
            int d = wave * 64 + dt * 16 + l16;
#pragma unroll
            for (int r = 0; r < 4; ++r)
                atomicAdd(outp + (size_t)(b + r) * 256 + d, acc[rt][dt][r]);
        }
}

extern "C" void kernel_launch(void* const* d_in, const int* in_sizes, int n_in,
                              void* d_out, int out_size, void* d_ws, size_t ws_size,
                              hipStream_t stream) {
    const float* nodes = (const float*)d_in[0];
    const int*   masks = (const int*)d_in[1];
    const float* Wt    = (const float*)d_in[2];
    const float* bt    = (const float*)d_in[3];
    const float* Wg    = (const float*)d_in[4];
    const float* bg    = (const float*)d_in[5];
    float* outp = (float*)d_out;

    // ws layout: h_t bf16 [256][200000] = 102,400,000 B; then Wt/Wg bf16 (131072 B)
    u16* h_t = (u16*)d_ws;
    u16* wtb = (u16*)((char*)d_ws + (size_t)102400000);
    u16* wgb = wtb + 65536;

    hipMemsetAsync(d_out, 0, (size_t)out_size * sizeof(float), stream);
    k_prep<<<dim3(256), dim3(256), 0, stream>>>(Wt, Wg, wtb, wgb);
    k_h<<<dim3(3125), dim3(256), 0, stream>>>(nodes, wtb, wgb, bt, bg, h_t);
    k_res<<<dim3(4, 157), dim3(256), 0, stream>>>(masks, h_t, outp);
}